// Round 3
// baseline (142.464 us; speedup 1.0000x reference)
//
#include <hip/hip_runtime.h>
#include <math.h>

typedef float f4 __attribute__((ext_vector_type(4)));

#define BDIM 256
#define WPB (BDIM / 64)
#define NBLOCKS 512

struct Pair {
    f4 aA0, aA1, cA0, cA1, aB0, aB1, cB0, cB1, uu;
};

struct WReg {
    f4 w0a, w0b, w0c, w0d, w1a, w1b, w1c, w1d;
    float b0, b1;
};

__device__ __forceinline__ float dot4(f4 a, f4 w) {
    return a[0]*w[0] + a[1]*w[1] + a[2]*w[2] + a[3]*w[3];
}

__device__ __forceinline__ void load_pair(Pair& P,
        const float* __restrict__ se1, const float* __restrict__ se2,
        const float* __restrict__ u, int pairIdx, int lane, bool extra)
{
    const int rowA = pairIdx * 2;
    const f4* pA1 = (const f4*)(se1 + (size_t)rowA * 300);
    const f4* pA2 = (const f4*)(se2 + (size_t)rowA * 300);
    const f4* pB1 = pA1 + 75;   // rowB = rowA+1, contiguous
    const f4* pB2 = pA2 + 75;
    const f4 zero = (f4)0.f;
    P.aA0 = __builtin_nontemporal_load(pA1 + lane);
    P.cA0 = __builtin_nontemporal_load(pA2 + lane);
    P.aB0 = __builtin_nontemporal_load(pB1 + lane);
    P.cB0 = __builtin_nontemporal_load(pB2 + lane);
    P.aA1 = zero; P.cA1 = zero; P.aB1 = zero; P.cB1 = zero;
    if (extra) {
        P.aA1 = __builtin_nontemporal_load(pA1 + 64 + lane);
        P.cA1 = __builtin_nontemporal_load(pA2 + 64 + lane);
        P.aB1 = __builtin_nontemporal_load(pB1 + 64 + lane);
        P.cB1 = __builtin_nontemporal_load(pB2 + 64 + lane);
    }
    P.uu = *(const f4*)(u + (size_t)rowA * 2);   // u for rowA(0,1) and rowB(2,3)
}

__device__ __forceinline__ void epilogue_row(float d0, float d1, float u0, float u1,
                                             float b0, float b1, float& s0, float& s1)
{
    float z0 = fmaxf(d0 + b0, 0.f);
    float z1 = fmaxf(d1 + b1, 0.f);
    float m  = fmaxf(z0, z1);
    float lse = m + logf(expf(z0 - m) + expf(z1 - m));
    float q0 = (z0 - lse) + (-logf(-logf(u0 + 1e-20f) + 1e-20f));
    float q1 = (z1 - lse) + (-logf(-logf(u1 + 1e-20f) + 1e-20f));
    float mm = fmaxf(q0, q1);
    float e0 = expf(q0 - mm);
    float e1 = expf(q1 - mm);
    float s  = e0 + e1;
    float y0 = e0 / s;
    float y1 = e1 / s;
    bool  pick0 = (q0 >= q1);                  // argmax, first index wins ties
    s0 = pick0 ? ((1.f - y0) + y0) : 0.f;      // ST fwd: exact 0 / (1-y)+y
    s1 = pick0 ? 0.f : ((1.f - y1) + y1);
}

__device__ __forceinline__ void proc_pair(const Pair& P, const WReg& WR,
        float* __restrict__ out, int pairIdx, int lane, bool extra)
{
    float dA0 = dot4(P.aA0, WR.w0a) + dot4(P.aA1, WR.w0b) + dot4(P.cA0, WR.w0c) + dot4(P.cA1, WR.w0d);
    float dA1 = dot4(P.aA0, WR.w1a) + dot4(P.aA1, WR.w1b) + dot4(P.cA0, WR.w1c) + dot4(P.cA1, WR.w1d);
    float dB0 = dot4(P.aB0, WR.w0a) + dot4(P.aB1, WR.w0b) + dot4(P.cB0, WR.w0c) + dot4(P.cB1, WR.w0d);
    float dB1 = dot4(P.aB0, WR.w1a) + dot4(P.aB1, WR.w1b) + dot4(P.cB0, WR.w1c) + dot4(P.cB1, WR.w1d);

    #pragma unroll
    for (int off = 32; off > 0; off >>= 1) {
        dA0 += __shfl_xor(dA0, off, 64);
        dA1 += __shfl_xor(dA1, off, 64);
        dB0 += __shfl_xor(dB0, off, 64);
        dB1 += __shfl_xor(dB1, off, 64);
    }

    float sA0, sA1, sB0, sB1;
    epilogue_row(dA0, dA1, P.uu[0], P.uu[1], WR.b0, WR.b1, sA0, sA1);
    epilogue_row(dB0, dB1, P.uu[2], P.uu[3], WR.b0, WR.b1, sB0, sB1);

    const int rowA = pairIdx * 2;
    f4* oA = (f4*)(out + (size_t)rowA * 600);
    f4* oB = oA + 150;
    __builtin_nontemporal_store(P.aA0 * sA0, oA + lane);
    __builtin_nontemporal_store(P.cA0 * sA1, oA + 75 + lane);
    __builtin_nontemporal_store(P.aB0 * sB0, oB + lane);
    __builtin_nontemporal_store(P.cB0 * sB1, oB + 75 + lane);
    if (extra) {
        __builtin_nontemporal_store(P.aA1 * sA0, oA + 64 + lane);
        __builtin_nontemporal_store(P.cA1 * sA1, oA + 139 + lane);
        __builtin_nontemporal_store(P.aB1 * sB0, oB + 64 + lane);
        __builtin_nontemporal_store(P.cB1 * sB1, oB + 139 + lane);
    }
}

__global__ __launch_bounds__(BDIM) void taskselector_kernel(
    const float* __restrict__ se1,
    const float* __restrict__ se2,
    const float* __restrict__ W,
    const float* __restrict__ bvec,
    const float* __restrict__ u,
    float* __restrict__ out,
    int Brows)
{
    const int lane   = threadIdx.x & 63;
    const int waveid = threadIdx.x >> 6;
    const int wglob  = blockIdx.x * WPB + waveid;
    const int nw     = gridDim.x * WPB;
    const bool extra = (lane < 11);
    const f4 zero = (f4)0.f;

    WReg WR;
    const f4* W0 = (const f4*)(W);
    const f4* W1 = (const f4*)(W + 600);
    WR.w0a = W0[lane];
    WR.w0b = extra ? W0[64 + lane]  : zero;
    WR.w0c = W0[75 + lane];
    WR.w0d = extra ? W0[139 + lane] : zero;
    WR.w1a = W1[lane];
    WR.w1b = extra ? W1[64 + lane]  : zero;
    WR.w1c = W1[75 + lane];
    WR.w1d = extra ? W1[139 + lane] : zero;
    WR.b0 = bvec[0];
    WR.b1 = bvec[1];

    // contiguous chunk of row-pairs per wave
    const int pairsTotal = Brows >> 1;
    const int ppw = pairsTotal / nw;
    const int rem = pairsTotal - ppw * nw;
    int i   = wglob * ppw + (wglob < rem ? wglob : rem);
    int cnt = ppw + (wglob < rem ? 1 : 0);

    if (cnt > 0) {
        const int end = i + cnt;
        Pair X, Y;
        load_pair(X, se1, se2, u, i, lane, extra);
        while (i + 2 < end) {
            load_pair(Y, se1, se2, u, i + 1, lane, extra);
            proc_pair(X, WR, out, i, lane, extra);
            load_pair(X, se1, se2, u, i + 2, lane, extra);
            proc_pair(Y, WR, out, i + 1, lane, extra);
            i += 2;
        }
        if (end - i == 2) {
            load_pair(Y, se1, se2, u, i + 1, lane, extra);
            proc_pair(X, WR, out, i, lane, extra);
            proc_pair(Y, WR, out, i + 1, lane, extra);
        } else {
            proc_pair(X, WR, out, i, lane, extra);
        }
    }

    // odd-row tail (not hit at B=131072, kept for generality)
    if ((Brows & 1) && wglob == 0) {
        const int row = Brows - 1;
        const f4* p1 = (const f4*)(se1 + (size_t)row * 300);
        const f4* p2 = (const f4*)(se2 + (size_t)row * 300);
        f4 a0 = p1[lane];
        f4 c0 = p2[lane];
        f4 a1 = extra ? p1[64 + lane] : zero;
        f4 c1 = extra ? p2[64 + lane] : zero;
        float d0 = dot4(a0, WR.w0a) + dot4(a1, WR.w0b) + dot4(c0, WR.w0c) + dot4(c1, WR.w0d);
        float d1 = dot4(a0, WR.w1a) + dot4(a1, WR.w1b) + dot4(c0, WR.w1c) + dot4(c1, WR.w1d);
        #pragma unroll
        for (int off = 32; off > 0; off >>= 1) {
            d0 += __shfl_xor(d0, off, 64);
            d1 += __shfl_xor(d1, off, 64);
        }
        float s0, s1;
        epilogue_row(d0, d1, u[(size_t)row * 2], u[(size_t)row * 2 + 1], WR.b0, WR.b1, s0, s1);
        f4* o = (f4*)(out + (size_t)row * 600);
        o[lane] = a0 * s0;
        o[75 + lane] = c0 * s1;
        if (extra) {
            o[64 + lane]  = a1 * s0;
            o[139 + lane] = c1 * s1;
        }
    }
}

extern "C" void kernel_launch(void* const* d_in, const int* in_sizes, int n_in,
                              void* d_out, int out_size, void* d_ws, size_t ws_size,
                              hipStream_t stream) {
    const float* se1 = (const float*)d_in[0];
    const float* se2 = (const float*)d_in[1];
    const float* W   = (const float*)d_in[2];
    const float* b   = (const float*)d_in[3];
    const float* u   = (const float*)d_in[4];
    float* out = (float*)d_out;

    const int Brows = in_sizes[0] / 300;   // 131072

    int blocks = NBLOCKS;                  // 2 blocks/CU, all resident
    int maxBlocks = ((Brows >> 1) + WPB - 1) / WPB;
    if (blocks > maxBlocks) blocks = maxBlocks;

    taskselector_kernel<<<blocks, BDIM, 0, stream>>>(se1, se2, W, b, u, out, Brows);
}

// Round 4
// 111.304 us; speedup vs baseline: 1.2799x; 1.2799x over previous
//
#include <hip/hip_runtime.h>
#include <math.h>

typedef float f4 __attribute__((ext_vector_type(4)));

#define BDIM 256
#define TROWS 16                 // rows per tile: 16*1200B = 19200B ≡ 0 (mod 128)
#define RPW 4                    // rows per wave (4 waves/block)
#define TILE_F4_IN 1200          // per-tensor f4 chunks per tile (16*300/4)
#define TILE_F4_OUT 2400         // out f4 chunks per tile (16*600/4)

__device__ __forceinline__ float dot4(f4 a, f4 w) {
    return a[0]*w[0] + a[1]*w[1] + a[2]*w[2] + a[3]*w[3];
}

__global__ __launch_bounds__(BDIM) void taskselector_kernel(
    const f4* __restrict__ se1,
    const f4* __restrict__ se2,
    const float* __restrict__ W,
    const float* __restrict__ bvec,
    const f4* __restrict__ u4,
    f4* __restrict__ out)
{
    __shared__ f4 L1[TILE_F4_IN];      // 19200 B
    __shared__ f4 L2[TILE_F4_IN];      // 19200 B
    __shared__ float SEL[TROWS * 2];   // 128 B
    __shared__ f4 UL[TROWS / 2];       // 32 floats of u

    const int tid  = threadIdx.x;
    const int lane = tid & 63;
    const int wave = tid >> 6;
    const int tile = blockIdx.x;

    // ---- W into regs (per lane), reused for all rows ----
    const bool extra = (lane < 11);
    const f4 zero = (f4)0.f;
    const f4* W0 = (const f4*)W;
    const f4* W1 = (const f4*)(W + 600);
    f4 w0a = W0[lane];
    f4 w0b = extra ? W0[64 + lane]  : zero;
    f4 w0c = W0[75 + lane];
    f4 w0d = extra ? W0[139 + lane] : zero;
    f4 w1a = W1[lane];
    f4 w1b = extra ? W1[64 + lane]  : zero;
    f4 w1c = W1[75 + lane];
    f4 w1d = extra ? W1[139 + lane] : zero;
    const float b0 = bvec[0];
    const float b1 = bvec[1];

    // ---- stage tile: flat, 128B-aligned, fully-coalesced ----
    const f4* s1 = se1 + (size_t)tile * TILE_F4_IN;
    const f4* s2 = se2 + (size_t)tile * TILE_F4_IN;
    f4 t[4], q[4];
    #pragma unroll
    for (int k = 0; k < 4; k++) t[k] = __builtin_nontemporal_load(s1 + k * BDIM + tid);
    #pragma unroll
    for (int k = 0; k < 4; k++) q[k] = __builtin_nontemporal_load(s2 + k * BDIM + tid);
    f4 t4 = zero, q4 = zero;
    if (tid < TILE_F4_IN - 4 * BDIM) {     // 176 threads
        t4 = __builtin_nontemporal_load(s1 + 4 * BDIM + tid);
        q4 = __builtin_nontemporal_load(s2 + 4 * BDIM + tid);
    }
    if (tid < TROWS / 2) UL[tid] = u4[(size_t)tile * (TROWS / 2) + tid];
    #pragma unroll
    for (int k = 0; k < 4; k++) L1[k * BDIM + tid] = t[k];
    #pragma unroll
    for (int k = 0; k < 4; k++) L2[k * BDIM + tid] = q[k];
    if (tid < TILE_F4_IN - 4 * BDIM) {
        L1[4 * BDIM + tid] = t4;
        L2[4 * BDIM + tid] = q4;
    }
    __syncthreads();

    // ---- compute selectors: wave w -> rows [w*4, w*4+4) ----
    const float* ULf = (const float*)UL;
    #pragma unroll
    for (int rr = 0; rr < RPW; rr++) {
        const int r = wave * RPW + rr;
        const f4* R1 = L1 + r * 75;
        const f4* R2 = L2 + r * 75;
        f4 a0 = R1[lane];
        f4 c0 = R2[lane];
        f4 a1 = extra ? R1[64 + lane] : zero;
        f4 c1 = extra ? R2[64 + lane] : zero;
        float d0 = dot4(a0, w0a) + dot4(a1, w0b) + dot4(c0, w0c) + dot4(c1, w0d);
        float d1 = dot4(a0, w1a) + dot4(a1, w1b) + dot4(c0, w1c) + dot4(c1, w1d);
        #pragma unroll
        for (int off = 32; off > 0; off >>= 1) {
            d0 += __shfl_xor(d0, off, 64);
            d1 += __shfl_xor(d1, off, 64);
        }
        // epilogue — identical formula to the proven (absmax 0.0) version
        float z0 = fmaxf(d0 + b0, 0.f);
        float z1 = fmaxf(d1 + b1, 0.f);
        float m  = fmaxf(z0, z1);
        float lse = m + logf(expf(z0 - m) + expf(z1 - m));
        float uu0 = ULf[2 * r];
        float uu1 = ULf[2 * r + 1];
        float q0 = (z0 - lse) + (-logf(-logf(uu0 + 1e-20f) + 1e-20f));
        float q1 = (z1 - lse) + (-logf(-logf(uu1 + 1e-20f) + 1e-20f));
        float mm = fmaxf(q0, q1);
        float e0 = expf(q0 - mm);
        float e1 = expf(q1 - mm);
        float s  = e0 + e1;
        float y0 = e0 / s;
        float y1 = e1 / s;
        bool  pick0 = (q0 >= q1);               // argmax, first index wins ties
        float s0 = pick0 ? ((1.f - y0) + y0) : 0.f;
        float s1v = pick0 ? 0.f : ((1.f - y1) + y1);
        if (lane == 0) { SEL[2 * r] = s0; SEL[2 * r + 1] = s1v; }
    }
    __syncthreads();

    // ---- gated store: flat, 128B-aligned, full lines only ----
    f4* o = out + (size_t)tile * TILE_F4_OUT;
    #pragma unroll
    for (int k = 0; k < 9; k++) {
        const int j   = k * BDIM + tid;
        const int row = j / 150;
        const int rem = j - row * 150;
        const bool first = (rem < 75);
        f4 v = first ? L1[row * 75 + rem] : L2[row * 75 + rem - 75];
        float sc = SEL[2 * row + (first ? 0 : 1)];
        __builtin_nontemporal_store(v * sc, o + j);
    }
    if (tid < TILE_F4_OUT - 9 * BDIM) {        // 96 threads
        const int j   = 9 * BDIM + tid;
        const int row = j / 150;
        const int rem = j - row * 150;
        const bool first = (rem < 75);
        f4 v = first ? L1[row * 75 + rem] : L2[row * 75 + rem - 75];
        float sc = SEL[2 * row + (first ? 0 : 1)];
        __builtin_nontemporal_store(v * sc, o + j);
    }
}

extern "C" void kernel_launch(void* const* d_in, const int* in_sizes, int n_in,
                              void* d_out, int out_size, void* d_ws, size_t ws_size,
                              hipStream_t stream) {
    const f4* se1 = (const f4*)d_in[0];
    const f4* se2 = (const f4*)d_in[1];
    const float* W = (const float*)d_in[2];
    const float* b = (const float*)d_in[3];
    const f4* u4  = (const f4*)d_in[4];
    f4* out = (f4*)d_out;

    const int Brows = in_sizes[0] / 300;     // 131072
    const int ntiles = Brows / TROWS;        // 8192 (exact for this problem)

    taskselector_kernel<<<ntiles, BDIM, 0, stream>>>(se1, se2, W, b, u4, out);
}